// Round 9
// baseline (365.761 us; speedup 1.0000x reference)
//
#include <hip/hip_runtime.h>
#include <hip/hip_bf16.h>

// Problem constants
#define BB   2
#define LL   2048
#define DD   2048
#define HH   16
#define KVH  4
#define HDD  128
#define RDD  64
#define MM   (BB*LL)   // 4096 rows of x

typedef __attribute__((ext_vector_type(4))) float f32x4;
typedef __attribute__((ext_vector_type(8))) short bf16x8;
typedef unsigned short u16;

static __device__ __forceinline__ u16 f2b(float f) {
  __hip_bfloat16 b = __float2bfloat16(f);
  return *(const u16*)&b;
}

// async global(16B/lane) -> LDS (wave-uniform base + lane*16)
static __device__ __forceinline__ void gload_lds16(const void* g, void* l) {
  __builtin_amdgcn_global_load_lds(
      (const __attribute__((address_space(1))) unsigned int*)g,
      (__attribute__((address_space(3))) unsigned int*)l, 16, 0, 0);
}

// ---------------- f32 -> bf16 cast (vectorized) ----------------
__global__ __launch_bounds__(256) void cast_bf16_kernel(const float* __restrict__ in,
                                                        u16* __restrict__ out, int n4) {
  int i = blockIdx.x * 256 + threadIdx.x;
  if (i >= n4) return;
  float4 v = ((const float4*)in)[i];
  ushort4 o;
  o.x = f2b(v.x); o.y = f2b(v.y); o.z = f2b(v.z); o.w = f2b(v.w);
  ((ushort4*)out)[i] = o;
}

// ---------------- small GEMM (N=64): C[M,N] = A @ W^T + bias ----------------
__global__ __launch_bounds__(64) void gemm_bf16_nt(const u16* __restrict__ A,
                                                   const u16* __restrict__ W,
                                                   const float* __restrict__ bias,
                                                   float* __restrict__ C,
                                                   int M, int N, int K) {
  const int n0 = blockIdx.x * 16;
  const int m0 = blockIdx.y * 16;
  const int lane = threadIdx.x;
  const int r  = lane & 15;
  const int kq = (lane >> 4) * 8;
  const u16* ap = A + (size_t)(m0 + r) * K + kq;
  const u16* wp = W + (size_t)(n0 + r) * K + kq;
  f32x4 acc = {0.f, 0.f, 0.f, 0.f};
  for (int k = 0; k < K; k += 32) {
    bf16x8 a = *(const bf16x8*)(ap + k);
    bf16x8 b = *(const bf16x8*)(wp + k);
    acc = __builtin_amdgcn_mfma_f32_16x16x32_bf16(a, b, acc, 0, 0, 0);
  }
  const int col = lane & 15;
  const int rg  = (lane >> 4) * 4;
  const float bv = bias[n0 + col];
#pragma unroll
  for (int i = 0; i < 4; ++i)
    C[(size_t)(m0 + rg + i) * N + (n0 + col)] = acc[i] + bv;
}

// ---------------- m97-style 128x128 tile GEMM ----
__global__ __launch_bounds__(256) void gemm128(const u16* __restrict__ A,
                                               const u16* __restrict__ W,
                                               const float* __restrict__ bias,
                                               float* __restrict__ C,
                                               int M, int N, int K) {
  __shared__ u16 As[128 * 32];
  __shared__ u16 Bs[128 * 32];
  const int w = threadIdx.x >> 6, lane = threadIdx.x & 63;
  const int r = lane & 15, hi = lane >> 4, rg = hi * 4;
  const int wm = w >> 1, wn = w & 1;
  const int m0 = blockIdx.y * 128, n0 = blockIdx.x * 128;
  const int srow = w * 32 + (lane >> 2);
  const int scb  = (lane & 3) * 16;
  f32x4 acc[4][4];
#pragma unroll
  for (int i = 0; i < 4; ++i)
#pragma unroll
    for (int j = 0; j < 4; ++j) acc[i][j] = (f32x4){0.f, 0.f, 0.f, 0.f};

  for (int k0 = 0; k0 < K; k0 += 32) {
#pragma unroll
    for (int i = 0; i < 2; ++i) {
      gload_lds16((const char*)(A + (size_t)(m0 + srow + i * 16) * K + k0) + scb,
                  (char*)As + (w * 2 + i) * 1024);
      gload_lds16((const char*)(W + (size_t)(n0 + srow + i * 16) * K + k0) + scb,
                  (char*)Bs + (w * 2 + i) * 1024);
    }
    __syncthreads();
    bf16x8 a[4], b[4];
#pragma unroll
    for (int i = 0; i < 4; ++i)
      a[i] = *(const bf16x8*)((const char*)As + (wm * 64 + i * 16 + r) * 64 + hi * 16);
#pragma unroll
    for (int j = 0; j < 4; ++j)
      b[j] = *(const bf16x8*)((const char*)Bs + (wn * 64 + j * 16 + r) * 64 + hi * 16);
#pragma unroll
    for (int i = 0; i < 4; ++i)
#pragma unroll
      for (int j = 0; j < 4; ++j)
        acc[i][j] = __builtin_amdgcn_mfma_f32_16x16x32_bf16(a[i], b[j], acc[i][j], 0, 0, 0);
    __syncthreads();
  }
#pragma unroll
  for (int j = 0; j < 4; ++j) {
    const float bv = bias[n0 + wn * 64 + j * 16 + r];
#pragma unroll
    for (int i = 0; i < 4; ++i)
#pragma unroll
      for (int ii = 0; ii < 4; ++ii)
        C[(size_t)(m0 + wm * 64 + i * 16 + rg + ii) * N + n0 + wn * 64 + j * 16 + r] =
            acc[i][j][ii] + bv;
  }
}

// log2(e)/sqrt(128): scores land in exp2 domain
#define QSCALE 0.1275174313f

// ---------------- build Qb in fragment-granule order ----------------
// Per q-tile (16 q) image 4KB: off_u16 = qt*2048 + ks*512 + hi*128 + r*8
__global__ __launch_bounds__(256) void build_q2(const float* __restrict__ qbuf,
                                                const float* __restrict__ cosb,
                                                const float* __restrict__ sinb,
                                                u16* __restrict__ Qb) {
  const int tid = blockIdx.x * 256 + threadIdx.x;   // granule id
  const int r  = tid & 15;
  const int hi = (tid >> 4) & 3;
  const int ks = (tid >> 6) & 3;
  const int qt = tid >> 8;                          // bh*128 + qtile
  const int qtile = qt & 127, bh = qt >> 7;
  const int h = bh & 15, b = bh >> 4;
  const int n = b * LL + qtile * 16 + r;
  const int d0 = ks * 32 + hi * 8;
  const float* qp = qbuf + (size_t)n * DD + h * HDD;
  float v[8];
  if (d0 < 64) {
#pragma unroll
    for (int j = 0; j < 8; ++j) v[j] = qp[d0 + j];
  } else {
    const int i0 = d0 - 64;
    const float* cb = cosb + (size_t)n * RDD + i0;
    const float* sb = sinb + (size_t)n * RDD + i0;
    if (i0 < 32) {
#pragma unroll
      for (int j = 0; j < 8; ++j) v[j] = qp[d0 + j] * cb[j] - qp[d0 + j + 32] * sb[j];
    } else {
#pragma unroll
      for (int j = 0; j < 8; ++j) v[j] = qp[d0 + j] * cb[j] + qp[d0 + j - 32] * sb[j];
    }
  }
  u16 o[8];
#pragma unroll
  for (int j = 0; j < 8; ++j) o[j] = f2b(v[j] * QSCALE);
  *(ushort4*)(Qb + (size_t)tid * 8)     = *(ushort4*)&o[0];
  *(ushort4*)(Qb + (size_t)tid * 8 + 4) = *(ushort4*)&o[4];
}

// ---------------- build Kb in tile-image order ----------------
// Per 64-key tile image 16KB: off_u16 = til*8192 + tt*2048 + ks*512 + hi*128 + r*8
__global__ __launch_bounds__(256) void build_k2(const float* __restrict__ kvbuf,
                                                const float* __restrict__ krbuf,
                                                const float* __restrict__ cosb,
                                                const float* __restrict__ sinb,
                                                u16* __restrict__ Kb) {
  const int tid = blockIdx.x * 256 + threadIdx.x;   // granule id
  const int r  = tid & 15;
  const int hi = (tid >> 4) & 3;
  const int ks = (tid >> 6) & 3;
  const int tt = (tid >> 8) & 3;
  const int til = tid >> 10;                        // bc*32 + stile
  const int stile = til & 31, bc = til >> 5;
  const int b = bc >> 2, c = bc & 3;
  const int s = stile * 64 + tt * 16 + r;
  const int n = b * LL + s;
  const int d0 = ks * 32 + hi * 8;
  float v[8];
  if (d0 < 64) {
    const float* kp = kvbuf + (size_t)n * (KVH * HDD) + c * HDD + d0;
#pragma unroll
    for (int j = 0; j < 8; ++j) v[j] = kp[j];
  } else {
    const int i0 = d0 - 64;
    const float* kr = krbuf + (size_t)n * RDD;
    const float* cb = cosb + (size_t)n * RDD + i0;
    const float* sb = sinb + (size_t)n * RDD + i0;
    if (i0 < 32) {
#pragma unroll
      for (int j = 0; j < 8; ++j) v[j] = kr[i0 + j] * cb[j] - kr[i0 + j + 32] * sb[j];
    } else {
#pragma unroll
      for (int j = 0; j < 8; ++j) v[j] = kr[i0 + j] * cb[j] + kr[i0 + j - 32] * sb[j];
    }
  }
  u16 o[8];
#pragma unroll
  for (int j = 0; j < 8; ++j) o[j] = f2b(v[j]);
  *(ushort4*)(Kb + (size_t)tid * 8)     = *(ushort4*)&o[0];
  *(ushort4*)(Kb + (size_t)tid * 8 + 4) = *(ushort4*)&o[4];
}

// ---------------- build VT in tile-image order (transpose via LDS) ----------------
__global__ __launch_bounds__(256) void build_v2(const float* __restrict__ kvbuf,
                                                u16* __restrict__ VT) {
  __shared__ float tile[64][132];
  const int til = blockIdx.x;                       // bc*32 + stile
  const int stile = til & 31, bc = til >> 5;
  const int b = bc >> 2, c = bc & 3;
  const int t = threadIdx.x;
#pragma unroll
  for (int it = 0; it < 8; ++it) {
    const int off = t * 4 + it * 1024;
    const int sl = off >> 7, d = off & 127;
    const float4 f = *(const float4*)(kvbuf + (size_t)(b * LL + stile * 64 + sl) * (KVH * HDD) + c * HDD + d);
    tile[sl][d] = f.x; tile[sl][d + 1] = f.y; tile[sl][d + 2] = f.z; tile[sl][d + 3] = f.w;
  }
  __syncthreads();
#pragma unroll
  for (int it = 0; it < 4; ++it) {
    const int g = t + it * 256;                     // 0..1023
    const int r = g & 15, hi = (g >> 4) & 3, j = g >> 6;
    const int d = (j >> 1) * 16 + r;
    const int sl0 = (j & 1) * 32 + hi * 8;
    u16 o[8];
#pragma unroll
    for (int j2 = 0; j2 < 8; ++j2) o[j2] = f2b(tile[sl0 + j2][d]);
    u16* dst = VT + (size_t)til * 8192 + (size_t)g * 8;
    *(ushort4*)dst = *(ushort4*)&o[0];
    *(ushort4*)(dst + 4) = *(ushort4*)&o[4];
  }
}

// ---------------- stage one 64-key V tile (16KB image) into LDS ----------------
static __device__ __forceinline__ void stage_v(const u16* Vt, u16* vbuf, int w, int lane) {
#pragma unroll
  for (int i = 0; i < 4; ++i) {
    const int j = w * 4 + i;                        // slot 0..15
    gload_lds16(Vt + (size_t)j * 512 + lane * 8, vbuf + j * 512);
  }
}

// ---------------- MFMA flash attention v6: K from L2 (global-direct), V in LDS ----------------
// grid 512; id mod 8 == bc -> all blocks of one (b,c) share an XCD's L2 (K/V 1MB + Q 2MB < 4MB).
// 4 waves x 32 q; KVB=64; V double-buffered in LDS; swapped QK^T; exp2 softmax; defer-max.
__global__ __launch_bounds__(256, 1) void attn_mfma6(const u16* __restrict__ Qb,
                                                     const u16* __restrict__ Kb,
                                                     const u16* __restrict__ VTb,
                                                     u16* __restrict__ attn_bf) {
  const int id = blockIdx.x;
  const int g = id & 31;
  const int strip = id >> 5;
  const int bc = g & 7, hlow = g >> 3;              // id%8 == bc -> XCD clustering
  const int b = bc >> 2, c = bc & 3;
  const int h = c * 4 + hlow;
  const int bh = b * 16 + h;
  const int qb = (strip < 8) ? (15 - strip) : (strip - 8);
  const int w = threadIdx.x >> 6, lane = threadIdx.x & 63;
  const int r = lane & 15, hi = lane >> 4, rg = hi * 4;
  const int q0 = qb * 128 + w * 32;

  __shared__ u16 Vs[2][8192];                       // 16KB x2
  __shared__ __align__(16) u16 Ps[4][2048];         // 4KB per wave

  const u16* Ktg = Kb + (size_t)(b * KVH + c) * 32 * 8192;   // per-(b,c) tile images
  const u16* Vtg = VTb + (size_t)(b * KVH + c) * 32 * 8192;

  // Q fragments (coalesced granule loads)
  bf16x8 qf[2][4];
#pragma unroll
  for (int qs = 0; qs < 2; ++qs) {
    const u16* qtb = Qb + (size_t)(bh * 128 + qb * 8 + w * 2 + qs) * 2048;
#pragma unroll
    for (int ks = 0; ks < 4; ++ks)
      qf[qs][ks] = *(const bf16x8*)(qtb + ks * 512 + lane * 8);
  }

  float m_[2] = {-3.0e38f, -3.0e38f}, l_[2] = {0.f, 0.f};
  f32x4 o[2][8];
#pragma unroll
  for (int qs = 0; qs < 2; ++qs)
#pragma unroll
    for (int t = 0; t < 8; ++t) o[qs][t] = (f32x4){0.f, 0.f, 0.f, 0.f};

  const int nt = 2 * qb + 2;                        // 64-key tiles (block-uniform)

  stage_v(Vtg, Vs[0], w, lane);
  __syncthreads();
  int cur = 0;

  for (int t = 0; t < nt; ++t) {
    const int s0 = t * 64;
    if (t + 1 < nt)
      stage_v(Vtg + (size_t)(t + 1) * 8192, Vs[cur ^ 1], w, lane);

    if (s0 <= q0 + 31) {                            // wave-uniform: skip fully-masked tiles
      const u16* Kt = Ktg + (size_t)t * 8192;       // K fragments straight from L2
      const u16* Vl = Vs[cur];

      // ---- swapped QK^T: st[qs][tt]: query col = r, key rows = tt*16 + rg + i ----
      f32x4 st[2][4];
#pragma unroll
      for (int qs = 0; qs < 2; ++qs)
#pragma unroll
        for (int tt = 0; tt < 4; ++tt) st[qs][tt] = (f32x4){0.f, 0.f, 0.f, 0.f};
      __builtin_amdgcn_s_setprio(1);
#pragma unroll
      for (int tt = 0; tt < 4; ++tt) {
        bf16x8 kf[4];
#pragma unroll
        for (int ks = 0; ks < 4; ++ks)
          kf[ks] = *(const bf16x8*)(Kt + tt * 2048 + ks * 512 + lane * 8);
#pragma unroll
        for (int qs = 0; qs < 2; ++qs)
#pragma unroll
          for (int ks = 0; ks < 4; ++ks)
            st[qs][tt] = __builtin_amdgcn_mfma_f32_16x16x32_bf16(kf[ks], qf[qs][ks], st[qs][tt], 0, 0, 0);
      }
      __builtin_amdgcn_s_setprio(0);

      // ---- causal mask ----
      if (s0 + 63 > q0) {
#pragma unroll
        for (int qs = 0; qs < 2; ++qs)
#pragma unroll
          for (int tt = 0; tt < 4; ++tt)
#pragma unroll
            for (int i = 0; i < 4; ++i)
              if (s0 + tt * 16 + rg + i > q0 + qs * 16 + r) st[qs][tt][i] = -3.0e38f;
      }

      // ---- in-lane max + 2 shuffles (exp2 domain) ----
      float vmax[2];
#pragma unroll
      for (int qs = 0; qs < 2; ++qs) {
        float v = st[qs][0][0];
#pragma unroll
        for (int tt = 0; tt < 4; ++tt)
#pragma unroll
          for (int i = 0; i < 4; ++i) v = fmaxf(v, st[qs][tt][i]);
        v = fmaxf(v, __shfl_xor(v, 16));
        v = fmaxf(v, __shfl_xor(v, 32));
        vmax[qs] = v;
      }
      // ---- defer-max rescale (thr 8 nats = 11.54 bits) ----
      const float grow = fmaxf(vmax[0] - m_[0], vmax[1] - m_[1]);
      if (!__all(grow <= 11.54f)) {
#pragma unroll
        for (int qs = 0; qs < 2; ++qs) {
          const float mn = fmaxf(m_[qs], vmax[qs]);
          const float cf = exp2f(m_[qs] - mn);
          l_[qs] *= cf;
          m_[qs] = mn;
#pragma unroll
          for (int tt = 0; tt < 8; ++tt)
#pragma unroll
            for (int i = 0; i < 4; ++i) o[qs][tt][i] *= cf;
        }
      }
      // ---- exp2, sum, pack P into granule layout ----
#pragma unroll
      for (int qs = 0; qs < 2; ++qs) {
        float ps = 0.f;
#pragma unroll
        for (int tt = 0; tt < 4; ++tt) {
          const float e0 = exp2f(st[qs][tt][0] - m_[qs]);
          const float e1 = exp2f(st[qs][tt][1] - m_[qs]);
          const float e2 = exp2f(st[qs][tt][2] - m_[qs]);
          const float e3 = exp2f(st[qs][tt][3] - m_[qs]);
          ps += (e0 + e1) + (e2 + e3);
          uint2 pw;
          pw.x = (unsigned)f2b(e0) | ((unsigned)f2b(e1) << 16);
          pw.y = (unsigned)f2b(e2) | ((unsigned)f2b(e3) << 16);
          const int k0 = tt * 16 + rg;              // keys k0..k0+3
          *(uint2*)&Ps[w][qs * 1024 + (k0 >> 5) * 512 + ((k0 >> 3) & 3) * 128 + r * 8 + (k0 & 7)] = pw;
        }
        ps += __shfl_xor(ps, 16);
        ps += __shfl_xor(ps, 32);
        l_[qs] += ps;
      }

      // ---- PV: O(32q x 128d) += P(32x64) @ V(64x128) ----
      bf16x8 pa[2][2];
#pragma unroll
      for (int qs = 0; qs < 2; ++qs)
#pragma unroll
        for (int kb = 0; kb < 2; ++kb)
          pa[qs][kb] = *(const bf16x8*)&Ps[w][qs * 1024 + kb * 512 + lane * 8];
      __builtin_amdgcn_s_setprio(1);
#pragma unroll
      for (int tt = 0; tt < 8; ++tt) {
#pragma unroll
        for (int kb = 0; kb < 2; ++kb) {
          bf16x8 vf = *(const bf16x8*)(Vl + tt * 1024 + kb * 512 + lane * 8);
#pragma unroll
          for (int qs = 0; qs < 2; ++qs)
            o[qs][tt] = __builtin_amdgcn_mfma_f32_16x16x32_bf16(pa[qs][kb], vf, o[qs][tt], 0, 0, 0);
        }
      }
      __builtin_amdgcn_s_setprio(0);
    }

    __syncthreads();
    cur ^= 1;
  }

  // ---- epilogue: l_ lives at query=r lanes; o rows are query=rg+i -> shuffle ----
#pragma unroll
  for (int qs = 0; qs < 2; ++qs) {
    const float il = 1.f / l_[qs];
    float inv[4];
#pragma unroll
    for (int i = 0; i < 4; ++i)
      inv[i] = __shfl(il, (lane & 48) + rg + i);
    u16* op = attn_bf + (size_t)(b * LL + q0 + qs * 16 + rg) * DD + h * HDD;
#pragma unroll
    for (int tt = 0; tt < 8; ++tt)
#pragma unroll
      for (int i = 0; i < 4; ++i)
        op[(size_t)i * DD + tt * 16 + r] = f2b(o[qs][tt][i] * inv[i]);
  }
}

extern "C" void kernel_launch(void* const* d_in, const int* in_sizes, int n_in,
                              void* d_out, int out_size, void* d_ws, size_t ws_size,
                              hipStream_t stream) {
  const float* x    = (const float*)d_in[0];
  const float* cosb = (const float*)d_in[1];
  const float* sinb = (const float*)d_in[2];
  const float* Wq   = (const float*)d_in[3];
  const float* bq   = (const float*)d_in[4];
  const float* Wkv  = (const float*)d_in[5];
  const float* bkv  = (const float*)d_in[6];
  const float* Wrk  = (const float*)d_in[7];
  const float* brk  = (const float*)d_in[8];
  const float* Wo   = (const float*)d_in[9];
  const float* bo   = (const float*)d_in[10];
  float* out = (float*)d_out;

  char* ws = (char*)d_ws;
  float* kvbuf = (float*)(ws);
  float* krbuf = (float*)(ws + 8388608);
  float* qbuf  = (float*)(ws + 9437184);
  u16*   attn_bf = (u16*)(ws + 9437184);
  u16*   xb    = (u16*)(ws + 42991616);
  u16*   Qb    = (u16*)(ws + 42991616);
  u16*   Wob   = (u16*)(ws + 59768832);
  u16*   Wkvb  = (u16*)(ws + 68157440);
  u16*   Wrkb  = (u16*)(ws + 70254592);
  u16*   Wqb   = (u16*)(ws + 70516736);
  u16*   Kb    = (u16*)(ws + 70516736);
  u16*   VTb   = (u16*)(ws + 74711040);

  // 1) casts to bf16
  cast_bf16_kernel<<<(MM * DD / 4) / 256, 256, 0, stream>>>(x, xb, MM * DD / 4);
  cast_bf16_kernel<<<(HH * HDD * DD / 4) / 256, 256, 0, stream>>>(Wq, Wqb, HH * HDD * DD / 4);
  cast_bf16_kernel<<<(KVH * HDD * DD / 4) / 256, 256, 0, stream>>>(Wkv, Wkvb, KVH * HDD * DD / 4);
  cast_bf16_kernel<<<(RDD * DD / 4) / 256, 256, 0, stream>>>(Wrk, Wrkb, RDD * DD / 4);
  cast_bf16_kernel<<<(DD * HH * HDD / 4) / 256, 256, 0, stream>>>(Wo, Wob, DD * HH * HDD / 4);

  // 2) input projections (f32 out)
  gemm128<<<dim3(DD / 128, MM / 128), 256, 0, stream>>>(xb, Wqb, bq, qbuf, MM, DD, DD);
  gemm128<<<dim3((KVH * HDD) / 128, MM / 128), 256, 0, stream>>>(xb, Wkvb, bkv, kvbuf, MM, KVH * HDD, DD);
  gemm_bf16_nt<<<dim3(RDD / 16, MM / 16), 64, 0, stream>>>(xb, Wrkb, brk, krbuf, MM, RDD, DD);

  // 3) build bf16 attention operands in fragment/tile-image layouts
  build_k2<<<(BB * KVH * LL * HDD / 8) / 256, 256, 0, stream>>>(kvbuf, krbuf, cosb, sinb, Kb);
  build_v2<<<BB * KVH * 32, 256, 0, stream>>>(kvbuf, VTb);
  build_q2<<<(MM * HH * HDD / 8) / 256, 256, 0, stream>>>(qbuf, cosb, sinb, Qb);

  // 4) MFMA flash attention v6 -> bf16
  attn_mfma6<<<dim3(512), 256, 0, stream>>>(Qb, Kb, VTb, attn_bf);

  // 5) output projection -> d_out (f32)
  gemm128<<<dim3(DD / 128, MM / 128), 256, 0, stream>>>(attn_bf, Wob, bo, out, MM, DD, DD);
}

// Round 10
// 344.818 us; speedup vs baseline: 1.0607x; 1.0607x over previous
//
#include <hip/hip_runtime.h>
#include <hip/hip_bf16.h>

// Problem constants
#define BB   2
#define LL   2048
#define DD   2048
#define HH   16
#define KVH  4
#define HDD  128
#define RDD  64
#define MM   (BB*LL)   // 4096 rows of x

typedef __attribute__((ext_vector_type(4))) float f32x4;
typedef __attribute__((ext_vector_type(8))) short bf16x8;
typedef unsigned short u16;

static __device__ __forceinline__ u16 f2b(float f) {
  __hip_bfloat16 b = __float2bfloat16(f);
  return *(const u16*)&b;
}

// async global(16B/lane) -> LDS (wave-uniform base + lane*16)
static __device__ __forceinline__ void gload_lds16(const void* g, void* l) {
  __builtin_amdgcn_global_load_lds(
      (const __attribute__((address_space(1))) unsigned int*)g,
      (__attribute__((address_space(3))) unsigned int*)l, 16, 0, 0);
}

// ---------------- f32 -> bf16 cast (vectorized) ----------------
__global__ __launch_bounds__(256) void cast_bf16_kernel(const float* __restrict__ in,
                                                        u16* __restrict__ out, int n4) {
  int i = blockIdx.x * 256 + threadIdx.x;
  if (i >= n4) return;
  float4 v = ((const float4*)in)[i];
  ushort4 o;
  o.x = f2b(v.x); o.y = f2b(v.y); o.z = f2b(v.z); o.w = f2b(v.w);
  ((ushort4*)out)[i] = o;
}

// ---------------- small GEMM (N=64): C[M,N] = A @ W^T + bias ----------------
__global__ __launch_bounds__(64) void gemm_bf16_nt(const u16* __restrict__ A,
                                                   const u16* __restrict__ W,
                                                   const float* __restrict__ bias,
                                                   float* __restrict__ C,
                                                   int M, int N, int K) {
  const int n0 = blockIdx.x * 16;
  const int m0 = blockIdx.y * 16;
  const int lane = threadIdx.x;
  const int r  = lane & 15;
  const int kq = (lane >> 4) * 8;
  const u16* ap = A + (size_t)(m0 + r) * K + kq;
  const u16* wp = W + (size_t)(n0 + r) * K + kq;
  f32x4 acc = {0.f, 0.f, 0.f, 0.f};
  for (int k = 0; k < K; k += 32) {
    bf16x8 a = *(const bf16x8*)(ap + k);
    bf16x8 b = *(const bf16x8*)(wp + k);
    acc = __builtin_amdgcn_mfma_f32_16x16x32_bf16(a, b, acc, 0, 0, 0);
  }
  const int col = lane & 15;
  const int rg  = (lane >> 4) * 4;
  const float bv = bias[n0 + col];
#pragma unroll
  for (int i = 0; i < 4; ++i)
    C[(size_t)(m0 + rg + i) * N + (n0 + col)] = acc[i] + bv;
}

// ---------------- m97-style 128x128 tile GEMM ----
__global__ __launch_bounds__(256) void gemm128(const u16* __restrict__ A,
                                               const u16* __restrict__ W,
                                               const float* __restrict__ bias,
                                               float* __restrict__ C,
                                               int M, int N, int K) {
  __shared__ u16 As[128 * 32];
  __shared__ u16 Bs[128 * 32];
  const int w = threadIdx.x >> 6, lane = threadIdx.x & 63;
  const int r = lane & 15, hi = lane >> 4, rg = hi * 4;
  const int wm = w >> 1, wn = w & 1;
  const int m0 = blockIdx.y * 128, n0 = blockIdx.x * 128;
  const int srow = w * 32 + (lane >> 2);
  const int scb  = (lane & 3) * 16;
  f32x4 acc[4][4];
#pragma unroll
  for (int i = 0; i < 4; ++i)
#pragma unroll
    for (int j = 0; j < 4; ++j) acc[i][j] = (f32x4){0.f, 0.f, 0.f, 0.f};

  for (int k0 = 0; k0 < K; k0 += 32) {
#pragma unroll
    for (int i = 0; i < 2; ++i) {
      gload_lds16((const char*)(A + (size_t)(m0 + srow + i * 16) * K + k0) + scb,
                  (char*)As + (w * 2 + i) * 1024);
      gload_lds16((const char*)(W + (size_t)(n0 + srow + i * 16) * K + k0) + scb,
                  (char*)Bs + (w * 2 + i) * 1024);
    }
    __syncthreads();
    bf16x8 a[4], b[4];
#pragma unroll
    for (int i = 0; i < 4; ++i)
      a[i] = *(const bf16x8*)((const char*)As + (wm * 64 + i * 16 + r) * 64 + hi * 16);
#pragma unroll
    for (int j = 0; j < 4; ++j)
      b[j] = *(const bf16x8*)((const char*)Bs + (wn * 64 + j * 16 + r) * 64 + hi * 16);
#pragma unroll
    for (int i = 0; i < 4; ++i)
#pragma unroll
      for (int j = 0; j < 4; ++j)
        acc[i][j] = __builtin_amdgcn_mfma_f32_16x16x32_bf16(a[i], b[j], acc[i][j], 0, 0, 0);
    __syncthreads();
  }
#pragma unroll
  for (int j = 0; j < 4; ++j) {
    const float bv = bias[n0 + wn * 64 + j * 16 + r];
#pragma unroll
    for (int i = 0; i < 4; ++i)
#pragma unroll
      for (int ii = 0; ii < 4; ++ii)
        C[(size_t)(m0 + wm * 64 + i * 16 + rg + ii) * N + n0 + wn * 64 + j * 16 + r] =
            acc[i][j][ii] + bv;
  }
}

// log2(e)/sqrt(128): scores land in exp2 domain
#define QSCALE 0.1275174313f

// ---------------- build Qb in fragment-granule order ----------------
// Per q-tile (16 q) image 4KB: off_u16 = qt*2048 + ks*512 + hi*128 + r*8
__global__ __launch_bounds__(256) void build_q2(const float* __restrict__ qbuf,
                                                const float* __restrict__ cosb,
                                                const float* __restrict__ sinb,
                                                u16* __restrict__ Qb) {
  const int tid = blockIdx.x * 256 + threadIdx.x;   // granule id
  const int r  = tid & 15;
  const int hi = (tid >> 4) & 3;
  const int ks = (tid >> 6) & 3;
  const int qt = tid >> 8;                          // bh*128 + qtile
  const int qtile = qt & 127, bh = qt >> 7;
  const int h = bh & 15, b = bh >> 4;
  const int n = b * LL + qtile * 16 + r;
  const int d0 = ks * 32 + hi * 8;
  const float* qp = qbuf + (size_t)n * DD + h * HDD;
  float v[8];
  if (d0 < 64) {
#pragma unroll
    for (int j = 0; j < 8; ++j) v[j] = qp[d0 + j];
  } else {
    const int i0 = d0 - 64;
    const float* cb = cosb + (size_t)n * RDD + i0;
    const float* sb = sinb + (size_t)n * RDD + i0;
    if (i0 < 32) {
#pragma unroll
      for (int j = 0; j < 8; ++j) v[j] = qp[d0 + j] * cb[j] - qp[d0 + j + 32] * sb[j];
    } else {
#pragma unroll
      for (int j = 0; j < 8; ++j) v[j] = qp[d0 + j] * cb[j] + qp[d0 + j - 32] * sb[j];
    }
  }
  u16 o[8];
#pragma unroll
  for (int j = 0; j < 8; ++j) o[j] = f2b(v[j] * QSCALE);
  *(ushort4*)(Qb + (size_t)tid * 8)     = *(ushort4*)&o[0];
  *(ushort4*)(Qb + (size_t)tid * 8 + 4) = *(ushort4*)&o[4];
}

// ---------------- build Kb in tile-image order ----------------
// Per 64-key tile image 16KB: off_u16 = til*8192 + tt*2048 + ks*512 + hi*128 + r*8
__global__ __launch_bounds__(256) void build_k2(const float* __restrict__ kvbuf,
                                                const float* __restrict__ krbuf,
                                                const float* __restrict__ cosb,
                                                const float* __restrict__ sinb,
                                                u16* __restrict__ Kb) {
  const int tid = blockIdx.x * 256 + threadIdx.x;   // granule id
  const int r  = tid & 15;
  const int hi = (tid >> 4) & 3;
  const int ks = (tid >> 6) & 3;
  const int tt = (tid >> 8) & 3;
  const int til = tid >> 10;                        // bc*32 + stile
  const int stile = til & 31, bc = til >> 5;
  const int b = bc >> 2, c = bc & 3;
  const int s = stile * 64 + tt * 16 + r;
  const int n = b * LL + s;
  const int d0 = ks * 32 + hi * 8;
  float v[8];
  if (d0 < 64) {
    const float* kp = kvbuf + (size_t)n * (KVH * HDD) + c * HDD + d0;
#pragma unroll
    for (int j = 0; j < 8; ++j) v[j] = kp[j];
  } else {
    const int i0 = d0 - 64;
    const float* kr = krbuf + (size_t)n * RDD;
    const float* cb = cosb + (size_t)n * RDD + i0;
    const float* sb = sinb + (size_t)n * RDD + i0;
    if (i0 < 32) {
#pragma unroll
      for (int j = 0; j < 8; ++j) v[j] = kr[i0 + j] * cb[j] - kr[i0 + j + 32] * sb[j];
    } else {
#pragma unroll
      for (int j = 0; j < 8; ++j) v[j] = kr[i0 + j] * cb[j] + kr[i0 + j - 32] * sb[j];
    }
  }
  u16 o[8];
#pragma unroll
  for (int j = 0; j < 8; ++j) o[j] = f2b(v[j]);
  *(ushort4*)(Kb + (size_t)tid * 8)     = *(ushort4*)&o[0];
  *(ushort4*)(Kb + (size_t)tid * 8 + 4) = *(ushort4*)&o[4];
}

// ---------------- build VT in tile-image order with INTERLEAVED keys ----------------
// Per 64-key tile image 16KB: chunk j6 = dtile*2 + kb at j6*512 + hi*128 + r*8.
// Granule word jj (jj=0..7): VT value V[key][d] with
//   key = kb*32 + (jj>>2)*16 + hi*4 + (jj&3),  d = dtile*16 + r.
// This key permutation matches the in-lane P fragment (pa) of attn_mfma7, so PV needs
// no cross-lane P exchange (permutation applied to both MFMA operands cancels).
__global__ __launch_bounds__(256) void build_v2(const float* __restrict__ kvbuf,
                                                u16* __restrict__ VT) {
  __shared__ float tile[64][132];
  const int til = blockIdx.x;                       // bc*32 + stile
  const int stile = til & 31, bc = til >> 5;
  const int b = bc >> 2, c = bc & 3;
  const int t = threadIdx.x;
#pragma unroll
  for (int it = 0; it < 8; ++it) {
    const int off = t * 4 + it * 1024;
    const int sl = off >> 7, d = off & 127;
    const float4 f = *(const float4*)(kvbuf + (size_t)(b * LL + stile * 64 + sl) * (KVH * HDD) + c * HDD + d);
    tile[sl][d] = f.x; tile[sl][d + 1] = f.y; tile[sl][d + 2] = f.z; tile[sl][d + 3] = f.w;
  }
  __syncthreads();
#pragma unroll
  for (int it = 0; it < 4; ++it) {
    const int g = t + it * 256;                     // 0..1023
    const int r = g & 15, hi = (g >> 4) & 3, j6 = g >> 6;
    const int d = (j6 >> 1) * 16 + r;
    const int kbase = (j6 & 1) * 32 + hi * 4;
    u16 o[8];
#pragma unroll
    for (int jj = 0; jj < 8; ++jj) {
      const int key = kbase + (jj >> 2) * 16 + (jj & 3);
      o[jj] = f2b(tile[key][d]);
    }
    u16* dst = VT + (size_t)til * 8192 + (size_t)g * 8;
    *(ushort4*)dst = *(ushort4*)&o[0];
    *(ushort4*)(dst + 4) = *(ushort4*)&o[4];
  }
}

// ---------------- stage one 64-key V tile (16KB image) into LDS, 8 waves ----------------
static __device__ __forceinline__ void stage_v8(const u16* Vt, u16* vbuf, int w, int lane) {
#pragma unroll
  for (int i = 0; i < 2; ++i) {
    const int j = w * 2 + i;                        // slot 0..15
    gload_lds16(Vt + (size_t)j * 512 + lane * 8, vbuf + j * 512);
  }
}

// ---------------- MFMA flash attention v7 ----------------
// 512 blocks x 512 threads (8 waves x 16 q rows). 4 waves/SIMD resident (VGPR<=128).
// K fragments direct from L2 (tile images); V double-buffered in LDS; in-lane P->PV
// via interleaved-key V images; swapped QK^T; exp2 softmax; defer-max.
__global__ __launch_bounds__(512, 4) void attn_mfma7(const u16* __restrict__ Qb,
                                                     const u16* __restrict__ Kb,
                                                     const u16* __restrict__ VTb,
                                                     u16* __restrict__ attn_bf) {
  const int id = blockIdx.x;
  const int g = id & 31;
  const int strip = id >> 5;
  const int bc = g & 7, hlow = g >> 3;              // id%8 == bc -> XCD clustering
  const int b = bc >> 2, c = bc & 3;
  const int h = c * 4 + hlow;
  const int bh = b * 16 + h;
  const int qb = (strip < 8) ? (15 - strip) : (strip - 8);
  const int w = threadIdx.x >> 6, lane = threadIdx.x & 63;
  const int r = lane & 15, hi = lane >> 4, rg = hi * 4;
  const int q0 = qb * 128 + w * 16;                 // this wave's 16 q rows

  __shared__ u16 Vs[2][8192];                       // 16KB x2 (no P buffer)

  const u16* Ktg = Kb + (size_t)(b * KVH + c) * 32 * 8192;
  const u16* Vtg = VTb + (size_t)(b * KVH + c) * 32 * 8192;

  // Q fragments (one q-tile per wave)
  bf16x8 qf[4];
  {
    const u16* qtb = Qb + (size_t)(bh * 128 + qb * 8 + w) * 2048;
#pragma unroll
    for (int ks = 0; ks < 4; ++ks)
      qf[ks] = *(const bf16x8*)(qtb + ks * 512 + lane * 8);
  }

  float m_ = -3.0e38f, l_ = 0.f;
  f32x4 o[8];
#pragma unroll
  for (int t = 0; t < 8; ++t) o[t] = (f32x4){0.f, 0.f, 0.f, 0.f};

  const int nt = 2 * qb + 2;                        // 64-key tiles (block-uniform)

  stage_v8(Vtg, Vs[0], w, lane);
  __syncthreads();
  int cur = 0;

  for (int t = 0; t < nt; ++t) {
    const int s0 = t * 64;
    if (t + 1 < nt)
      stage_v8(Vtg + (size_t)(t + 1) * 8192, Vs[cur ^ 1], w, lane);

    if (s0 <= q0 + 15) {                            // wave-uniform skip of masked tiles
      const u16* Kt = Ktg + (size_t)t * 8192;       // K fragments from L2

      // ---- swapped QK^T: st[tt]: query col = r, key rows = tt*16 + rg + i ----
      f32x4 st[4];
#pragma unroll
      for (int tt = 0; tt < 4; ++tt) st[tt] = (f32x4){0.f, 0.f, 0.f, 0.f};
      __builtin_amdgcn_s_setprio(1);
#pragma unroll
      for (int tt = 0; tt < 4; ++tt) {
        bf16x8 kf[4];
#pragma unroll
        for (int ks = 0; ks < 4; ++ks)
          kf[ks] = *(const bf16x8*)(Kt + tt * 2048 + ks * 512 + lane * 8);
#pragma unroll
        for (int ks = 0; ks < 4; ++ks)
          st[tt] = __builtin_amdgcn_mfma_f32_16x16x32_bf16(kf[ks], qf[ks], st[tt], 0, 0, 0);
      }
      __builtin_amdgcn_s_setprio(0);

      // ---- causal mask ----
      if (s0 + 63 > q0) {
#pragma unroll
        for (int tt = 0; tt < 4; ++tt)
#pragma unroll
          for (int i = 0; i < 4; ++i)
            if (s0 + tt * 16 + rg + i > q0 + r) st[tt][i] = -3.0e38f;
      }

      // ---- in-lane max + 2 shuffles (exp2 domain) ----
      float vmax = st[0][0];
#pragma unroll
      for (int tt = 0; tt < 4; ++tt)
#pragma unroll
        for (int i = 0; i < 4; ++i) vmax = fmaxf(vmax, st[tt][i]);
      vmax = fmaxf(vmax, __shfl_xor(vmax, 16));
      vmax = fmaxf(vmax, __shfl_xor(vmax, 32));

      // ---- defer-max rescale (thr 8 nats = 11.54 bits) ----
      if (!__all(vmax - m_ <= 11.54f)) {
        const float mn = fmaxf(m_, vmax);
        const float cf = exp2f(m_ - mn);
        l_ *= cf;
        m_ = mn;
#pragma unroll
        for (int tt = 0; tt < 8; ++tt)
#pragma unroll
          for (int i = 0; i < 4; ++i) o[tt][i] *= cf;
      }

      // ---- exp2 + sum + in-lane P fragments (no LDS) ----
      float e[4][4];
      float ps = 0.f;
#pragma unroll
      for (int tt = 0; tt < 4; ++tt)
#pragma unroll
        for (int i = 0; i < 4; ++i) {
          e[tt][i] = exp2f(st[tt][i] - m_);
          ps += e[tt][i];
        }
      ps += __shfl_xor(ps, 16);
      ps += __shfl_xor(ps, 32);
      l_ += ps;

      bf16x8 pa[2];
#pragma unroll
      for (int kb = 0; kb < 2; ++kb) {
        bf16x8 v;
#pragma unroll
        for (int j = 0; j < 8; ++j)
          v[j] = (short)f2b(e[2 * kb + (j >> 2)][j & 3]);
        pa[kb] = v;
      }

      // ---- PV: O(16q x 128d) += P(16x64) @ V(64x128), keys interleaved in both ----
      const u16* Vl = Vs[cur];
      __builtin_amdgcn_s_setprio(1);
#pragma unroll
      for (int tt = 0; tt < 8; ++tt) {
#pragma unroll
        for (int kb = 0; kb < 2; ++kb) {
          bf16x8 vf = *(const bf16x8*)(Vl + tt * 1024 + kb * 512 + lane * 8);
          o[tt] = __builtin_amdgcn_mfma_f32_16x16x32_bf16(pa[kb], vf, o[tt], 0, 0, 0);
        }
      }
      __builtin_amdgcn_s_setprio(0);
    }

    __syncthreads();
    cur ^= 1;
  }

  // ---- epilogue: l_ lives at query=r lanes; o rows are query=rg+i -> shuffle ----
  const float il = 1.f / l_;
  float inv[4];
#pragma unroll
  for (int i = 0; i < 4; ++i)
    inv[i] = __shfl(il, (lane & 48) + rg + i);
  u16* op = attn_bf + (size_t)(b * LL + q0 + rg) * DD + h * HDD;
#pragma unroll
  for (int tt = 0; tt < 8; ++tt)
#pragma unroll
    for (int i = 0; i < 4; ++i)
      op[(size_t)i * DD + tt * 16 + r] = f2b(o[tt][i] * inv[i]);
}

extern "C" void kernel_launch(void* const* d_in, const int* in_sizes, int n_in,
                              void* d_out, int out_size, void* d_ws, size_t ws_size,
                              hipStream_t stream) {
  const float* x    = (const float*)d_in[0];
  const float* cosb = (const float*)d_in[1];
  const float* sinb = (const float*)d_in[2];
  const float* Wq   = (const float*)d_in[3];
  const float* bq   = (const float*)d_in[4];
  const float* Wkv  = (const float*)d_in[5];
  const float* bkv  = (const float*)d_in[6];
  const float* Wrk  = (const float*)d_in[7];
  const float* brk  = (const float*)d_in[8];
  const float* Wo   = (const float*)d_in[9];
  const float* bo   = (const float*)d_in[10];
  float* out = (float*)d_out;

  char* ws = (char*)d_ws;
  float* kvbuf = (float*)(ws);
  float* krbuf = (float*)(ws + 8388608);
  float* qbuf  = (float*)(ws + 9437184);
  u16*   attn_bf = (u16*)(ws + 9437184);
  u16*   xb    = (u16*)(ws + 42991616);
  u16*   Qb    = (u16*)(ws + 42991616);
  u16*   Wob   = (u16*)(ws + 59768832);
  u16*   Wkvb  = (u16*)(ws + 68157440);
  u16*   Wrkb  = (u16*)(ws + 70254592);
  u16*   Wqb   = (u16*)(ws + 70516736);
  u16*   Kb    = (u16*)(ws + 70516736);
  u16*   VTb   = (u16*)(ws + 74711040);

  // 1) casts to bf16
  cast_bf16_kernel<<<(MM * DD / 4) / 256, 256, 0, stream>>>(x, xb, MM * DD / 4);
  cast_bf16_kernel<<<(HH * HDD * DD / 4) / 256, 256, 0, stream>>>(Wq, Wqb, HH * HDD * DD / 4);
  cast_bf16_kernel<<<(KVH * HDD * DD / 4) / 256, 256, 0, stream>>>(Wkv, Wkvb, KVH * HDD * DD / 4);
  cast_bf16_kernel<<<(RDD * DD / 4) / 256, 256, 0, stream>>>(Wrk, Wrkb, RDD * DD / 4);
  cast_bf16_kernel<<<(DD * HH * HDD / 4) / 256, 256, 0, stream>>>(Wo, Wob, DD * HH * HDD / 4);

  // 2) input projections (f32 out)
  gemm128<<<dim3(DD / 128, MM / 128), 256, 0, stream>>>(xb, Wqb, bq, qbuf, MM, DD, DD);
  gemm128<<<dim3((KVH * HDD) / 128, MM / 128), 256, 0, stream>>>(xb, Wkvb, bkv, kvbuf, MM, KVH * HDD, DD);
  gemm_bf16_nt<<<dim3(RDD / 16, MM / 16), 64, 0, stream>>>(xb, Wrkb, brk, krbuf, MM, RDD, DD);

  // 3) build bf16 attention operands in fragment/tile-image layouts
  build_k2<<<(BB * KVH * LL * HDD / 8) / 256, 256, 0, stream>>>(kvbuf, krbuf, cosb, sinb, Kb);
  build_v2<<<BB * KVH * 32, 256, 0, stream>>>(kvbuf, VTb);
  build_q2<<<(MM * HH * HDD / 8) / 256, 256, 0, stream>>>(qbuf, cosb, sinb, Qb);

  // 4) MFMA flash attention v7 -> bf16
  attn_mfma7<<<dim3(512), 512, 0, stream>>>(Qb, Kb, VTb, attn_bf);

  // 5) output projection -> d_out (f32)
  gemm128<<<dim3(DD / 128, MM / 128), 256, 0, stream>>>(attn_bf, Wob, bo, out, MM, DD, DD);
}

// Round 11
// 293.345 us; speedup vs baseline: 1.2469x; 1.1755x over previous
//
#include <hip/hip_runtime.h>
#include <hip/hip_bf16.h>

// Problem constants
#define BB   2
#define LL   2048
#define DD   2048
#define HH   16
#define KVH  4
#define HDD  128
#define RDD  64
#define MM   (BB*LL)   // 4096 rows of x

typedef __attribute__((ext_vector_type(4))) float f32x4;
typedef __attribute__((ext_vector_type(8))) short bf16x8;
typedef unsigned short u16;

static __device__ __forceinline__ u16 f2b(float f) {
  __hip_bfloat16 b = __float2bfloat16(f);
  return *(const u16*)&b;
}

// async global(16B/lane) -> LDS (wave-uniform base + lane*16)
static __device__ __forceinline__ void gload_lds16(const void* g, void* l) {
  __builtin_amdgcn_global_load_lds(
      (const __attribute__((address_space(1))) unsigned int*)g,
      (__attribute__((address_space(3))) unsigned int*)l, 16, 0, 0);
}

// ---------------- f32 -> bf16 cast (vectorized) ----------------
__global__ __launch_bounds__(256) void cast_bf16_kernel(const float* __restrict__ in,
                                                        u16* __restrict__ out, int n4) {
  int i = blockIdx.x * 256 + threadIdx.x;
  if (i >= n4) return;
  float4 v = ((const float4*)in)[i];
  ushort4 o;
  o.x = f2b(v.x); o.y = f2b(v.y); o.z = f2b(v.z); o.w = f2b(v.w);
  ((ushort4*)out)[i] = o;
}

// ---------------- small GEMM (N=64): C[M,N] = A @ W^T + bias ----------------
__global__ __launch_bounds__(64) void gemm_bf16_nt(const u16* __restrict__ A,
                                                   const u16* __restrict__ W,
                                                   const float* __restrict__ bias,
                                                   float* __restrict__ C,
                                                   int M, int N, int K) {
  const int n0 = blockIdx.x * 16;
  const int m0 = blockIdx.y * 16;
  const int lane = threadIdx.x;
  const int r  = lane & 15;
  const int kq = (lane >> 4) * 8;
  const u16* ap = A + (size_t)(m0 + r) * K + kq;
  const u16* wp = W + (size_t)(n0 + r) * K + kq;
  f32x4 acc = {0.f, 0.f, 0.f, 0.f};
  for (int k = 0; k < K; k += 32) {
    bf16x8 a = *(const bf16x8*)(ap + k);
    bf16x8 b = *(const bf16x8*)(wp + k);
    acc = __builtin_amdgcn_mfma_f32_16x16x32_bf16(a, b, acc, 0, 0, 0);
  }
  const int col = lane & 15;
  const int rg  = (lane >> 4) * 4;
  const float bv = bias[n0 + col];
#pragma unroll
  for (int i = 0; i < 4; ++i)
    C[(size_t)(m0 + rg + i) * N + (n0 + col)] = acc[i] + bv;
}

// ---------------- m97-style 128x128 tile GEMM ----
__global__ __launch_bounds__(256) void gemm128(const u16* __restrict__ A,
                                               const u16* __restrict__ W,
                                               const float* __restrict__ bias,
                                               float* __restrict__ C,
                                               int M, int N, int K) {
  __shared__ u16 As[128 * 32];
  __shared__ u16 Bs[128 * 32];
  const int w = threadIdx.x >> 6, lane = threadIdx.x & 63;
  const int r = lane & 15, hi = lane >> 4, rg = hi * 4;
  const int wm = w >> 1, wn = w & 1;
  const int m0 = blockIdx.y * 128, n0 = blockIdx.x * 128;
  const int srow = w * 32 + (lane >> 2);
  const int scb  = (lane & 3) * 16;
  f32x4 acc[4][4];
#pragma unroll
  for (int i = 0; i < 4; ++i)
#pragma unroll
    for (int j = 0; j < 4; ++j) acc[i][j] = (f32x4){0.f, 0.f, 0.f, 0.f};

  for (int k0 = 0; k0 < K; k0 += 32) {
#pragma unroll
    for (int i = 0; i < 2; ++i) {
      gload_lds16((const char*)(A + (size_t)(m0 + srow + i * 16) * K + k0) + scb,
                  (char*)As + (w * 2 + i) * 1024);
      gload_lds16((const char*)(W + (size_t)(n0 + srow + i * 16) * K + k0) + scb,
                  (char*)Bs + (w * 2 + i) * 1024);
    }
    __syncthreads();
    bf16x8 a[4], b[4];
#pragma unroll
    for (int i = 0; i < 4; ++i)
      a[i] = *(const bf16x8*)((const char*)As + (wm * 64 + i * 16 + r) * 64 + hi * 16);
#pragma unroll
    for (int j = 0; j < 4; ++j)
      b[j] = *(const bf16x8*)((const char*)Bs + (wn * 64 + j * 16 + r) * 64 + hi * 16);
#pragma unroll
    for (int i = 0; i < 4; ++i)
#pragma unroll
      for (int j = 0; j < 4; ++j)
        acc[i][j] = __builtin_amdgcn_mfma_f32_16x16x32_bf16(a[i], b[j], acc[i][j], 0, 0, 0);
    __syncthreads();
  }
#pragma unroll
  for (int j = 0; j < 4; ++j) {
    const float bv = bias[n0 + wn * 64 + j * 16 + r];
#pragma unroll
    for (int i = 0; i < 4; ++i)
#pragma unroll
      for (int ii = 0; ii < 4; ++ii)
        C[(size_t)(m0 + wm * 64 + i * 16 + rg + ii) * N + n0 + wn * 64 + j * 16 + r] =
            acc[i][j][ii] + bv;
  }
}

// log2(e)/sqrt(128): scores land in exp2 domain
#define QSCALE 0.1275174313f

// ---------------- build Qb in fragment-granule order ----------------
// Per q-tile (16 q) image 4KB: off_u16 = qt*2048 + ks*512 + hi*128 + r*8
__global__ __launch_bounds__(256) void build_q2(const float* __restrict__ qbuf,
                                                const float* __restrict__ cosb,
                                                const float* __restrict__ sinb,
                                                u16* __restrict__ Qb) {
  const int tid = blockIdx.x * 256 + threadIdx.x;   // granule id
  const int r  = tid & 15;
  const int hi = (tid >> 4) & 3;
  const int ks = (tid >> 6) & 3;
  const int qt = tid >> 8;                          // bh*128 + qtile
  const int qtile = qt & 127, bh = qt >> 7;
  const int h = bh & 15, b = bh >> 4;
  const int n = b * LL + qtile * 16 + r;
  const int d0 = ks * 32 + hi * 8;
  const float* qp = qbuf + (size_t)n * DD + h * HDD;
  float v[8];
  if (d0 < 64) {
#pragma unroll
    for (int j = 0; j < 8; ++j) v[j] = qp[d0 + j];
  } else {
    const int i0 = d0 - 64;
    const float* cb = cosb + (size_t)n * RDD + i0;
    const float* sb = sinb + (size_t)n * RDD + i0;
    if (i0 < 32) {
#pragma unroll
      for (int j = 0; j < 8; ++j) v[j] = qp[d0 + j] * cb[j] - qp[d0 + j + 32] * sb[j];
    } else {
#pragma unroll
      for (int j = 0; j < 8; ++j) v[j] = qp[d0 + j] * cb[j] + qp[d0 + j - 32] * sb[j];
    }
  }
  u16 o[8];
#pragma unroll
  for (int j = 0; j < 8; ++j) o[j] = f2b(v[j] * QSCALE);
  *(ushort4*)(Qb + (size_t)tid * 8)     = *(ushort4*)&o[0];
  *(ushort4*)(Qb + (size_t)tid * 8 + 4) = *(ushort4*)&o[4];
}

// ---------------- build Kb in tile-image order ----------------
// Per 64-key tile image 16KB: off_u16 = til*8192 + tt*2048 + ks*512 + hi*128 + r*8
__global__ __launch_bounds__(256) void build_k2(const float* __restrict__ kvbuf,
                                                const float* __restrict__ krbuf,
                                                const float* __restrict__ cosb,
                                                const float* __restrict__ sinb,
                                                u16* __restrict__ Kb) {
  const int tid = blockIdx.x * 256 + threadIdx.x;   // granule id
  const int r  = tid & 15;
  const int hi = (tid >> 4) & 3;
  const int ks = (tid >> 6) & 3;
  const int tt = (tid >> 8) & 3;
  const int til = tid >> 10;                        // bc*32 + stile
  const int stile = til & 31, bc = til >> 5;
  const int b = bc >> 2, c = bc & 3;
  const int s = stile * 64 + tt * 16 + r;
  const int n = b * LL + s;
  const int d0 = ks * 32 + hi * 8;
  float v[8];
  if (d0 < 64) {
    const float* kp = kvbuf + (size_t)n * (KVH * HDD) + c * HDD + d0;
#pragma unroll
    for (int j = 0; j < 8; ++j) v[j] = kp[j];
  } else {
    const int i0 = d0 - 64;
    const float* kr = krbuf + (size_t)n * RDD;
    const float* cb = cosb + (size_t)n * RDD + i0;
    const float* sb = sinb + (size_t)n * RDD + i0;
    if (i0 < 32) {
#pragma unroll
      for (int j = 0; j < 8; ++j) v[j] = kr[i0 + j] * cb[j] - kr[i0 + j + 32] * sb[j];
    } else {
#pragma unroll
      for (int j = 0; j < 8; ++j) v[j] = kr[i0 + j] * cb[j] + kr[i0 + j - 32] * sb[j];
    }
  }
  u16 o[8];
#pragma unroll
  for (int j = 0; j < 8; ++j) o[j] = f2b(v[j]);
  *(ushort4*)(Kb + (size_t)tid * 8)     = *(ushort4*)&o[0];
  *(ushort4*)(Kb + (size_t)tid * 8 + 4) = *(ushort4*)&o[4];
}

// ---------------- build VT in tile-image order with INTERLEAVED keys ----------------
// Per 64-key tile image 16KB: chunk j6 = dtile*2 + kb at j6*512 + hi*128 + r*8.
// Granule word jj: VT value V[key][d], key = kb*32 + (jj>>2)*16 + hi*4 + (jj&3),
// d = dtile*16 + r. Matches the in-lane P fragment of the attention kernel.
__global__ __launch_bounds__(256) void build_v2(const float* __restrict__ kvbuf,
                                                u16* __restrict__ VT) {
  __shared__ float tile[64][132];
  const int til = blockIdx.x;                       // bc*32 + stile
  const int stile = til & 31, bc = til >> 5;
  const int b = bc >> 2, c = bc & 3;
  const int t = threadIdx.x;
#pragma unroll
  for (int it = 0; it < 8; ++it) {
    const int off = t * 4 + it * 1024;
    const int sl = off >> 7, d = off & 127;
    const float4 f = *(const float4*)(kvbuf + (size_t)(b * LL + stile * 64 + sl) * (KVH * HDD) + c * HDD + d);
    tile[sl][d] = f.x; tile[sl][d + 1] = f.y; tile[sl][d + 2] = f.z; tile[sl][d + 3] = f.w;
  }
  __syncthreads();
#pragma unroll
  for (int it = 0; it < 4; ++it) {
    const int g = t + it * 256;                     // 0..1023
    const int r = g & 15, hi = (g >> 4) & 3, j6 = g >> 6;
    const int d = (j6 >> 1) * 16 + r;
    const int kbase = (j6 & 1) * 32 + hi * 4;
    u16 o[8];
#pragma unroll
    for (int jj = 0; jj < 8; ++jj) {
      const int key = kbase + (jj >> 2) * 16 + (jj & 3);
      o[jj] = f2b(tile[key][d]);
    }
    u16* dst = VT + (size_t)til * 8192 + (size_t)g * 8;
    *(ushort4*)dst = *(ushort4*)&o[0];
    *(ushort4*)(dst + 4) = *(ushort4*)&o[4];
  }
}

// ---------------- stage one 64-key tile (K+V images, 16KB each), 8 waves ----------------
static __device__ __forceinline__ void stage_kv8(const u16* Kt, const u16* Vt,
                                                 u16* kbuf, u16* vbuf, int w, int lane) {
#pragma unroll
  for (int i = 0; i < 2; ++i) {
    const int j = w * 2 + i;                        // slot 0..15
    gload_lds16(Kt + (size_t)j * 512 + lane * 8, kbuf + j * 512);
    gload_lds16(Vt + (size_t)j * 512 + lane * 8, vbuf + j * 512);
  }
}

// ---------------- MFMA flash attention v8 ----------------
// 256 blocks x 512 threads (8 waves x 32 q rows = 256 rows = one heavy+light qb pair).
// Waves 0-3: qb=15-s (heavy); waves 4-7: qb=s (light) -> uniform per-block work.
// K and V staged in LDS (8-way shared, double-buffered); in-lane P via interleaved-key
// V images; swapped QK^T; exp2 softmax; defer-max.
__global__ __launch_bounds__(512, 2) void attn_mfma8(const u16* __restrict__ Qb,
                                                     const u16* __restrict__ Kb,
                                                     const u16* __restrict__ VTb,
                                                     u16* __restrict__ attn_bf) {
  const int id = blockIdx.x;
  const int g = id & 31;
  const int s = id >> 5;                            // 0..7
  const int bc = g & 7, hlow = g >> 3;              // id%8 == bc -> XCD clustering
  const int b = bc >> 2, c = bc & 3;
  const int h = c * 4 + hlow;
  const int bh = b * 16 + h;
  const int w = threadIdx.x >> 6, lane = threadIdx.x & 63;
  const int r = lane & 15, hi = lane >> 4, rg = hi * 4;
  const int qb = (w < 4) ? (15 - s) : s;
  const int q0 = qb * 128 + (w & 3) * 32;           // this wave's 32 q rows
  const int nt = 2 * (15 - s) + 2;                  // block-uniform loop length (heavy)

  __shared__ u16 Ks[2][8192];                       // 16KB x2
  __shared__ u16 Vs[2][8192];                       // 16KB x2

  const u16* Ktg = Kb + (size_t)(b * KVH + c) * 32 * 8192;
  const u16* Vtg = VTb + (size_t)(b * KVH + c) * 32 * 8192;

  // Q fragments: two 16-row q-subtiles per wave
  bf16x8 qf[2][4];
#pragma unroll
  for (int qs = 0; qs < 2; ++qs) {
    const u16* qtb = Qb + (size_t)(bh * 128 + qb * 8 + (w & 3) * 2 + qs) * 2048;
#pragma unroll
    for (int ks = 0; ks < 4; ++ks)
      qf[qs][ks] = *(const bf16x8*)(qtb + ks * 512 + lane * 8);
  }

  float m_[2] = {-3.0e38f, -3.0e38f}, l_[2] = {0.f, 0.f};
  f32x4 o[2][8];
#pragma unroll
  for (int qs = 0; qs < 2; ++qs)
#pragma unroll
    for (int t = 0; t < 8; ++t) o[qs][t] = (f32x4){0.f, 0.f, 0.f, 0.f};

  stage_kv8(Ktg, Vtg, Ks[0], Vs[0], w, lane);
  __syncthreads();
  int cur = 0;

  for (int t = 0; t < nt; ++t) {
    const int s0 = t * 64;
    if (t + 1 < nt)
      stage_kv8(Ktg + (size_t)(t + 1) * 8192, Vtg + (size_t)(t + 1) * 8192,
                Ks[cur ^ 1], Vs[cur ^ 1], w, lane);

    if (s0 <= q0 + 31) {                            // wave-uniform skip of masked tiles
      const u16* Kl = Ks[cur];
      const u16* Vl = Vs[cur];

      // ---- swapped QK^T: st[qs][tt]: query col = r, key rows = tt*16 + rg + i ----
      f32x4 st[2][4];
#pragma unroll
      for (int qs = 0; qs < 2; ++qs)
#pragma unroll
        for (int tt = 0; tt < 4; ++tt) st[qs][tt] = (f32x4){0.f, 0.f, 0.f, 0.f};
      __builtin_amdgcn_s_setprio(1);
#pragma unroll
      for (int tt = 0; tt < 4; ++tt) {
        bf16x8 kf[4];
#pragma unroll
        for (int ks = 0; ks < 4; ++ks)
          kf[ks] = *(const bf16x8*)(Kl + tt * 2048 + ks * 512 + lane * 8);
#pragma unroll
        for (int qs = 0; qs < 2; ++qs)
#pragma unroll
          for (int ks = 0; ks < 4; ++ks)
            st[qs][tt] = __builtin_amdgcn_mfma_f32_16x16x32_bf16(kf[ks], qf[qs][ks], st[qs][tt], 0, 0, 0);
      }
      __builtin_amdgcn_s_setprio(0);

      // ---- causal mask ----
      if (s0 + 63 > q0) {
#pragma unroll
        for (int qs = 0; qs < 2; ++qs)
#pragma unroll
          for (int tt = 0; tt < 4; ++tt)
#pragma unroll
            for (int i = 0; i < 4; ++i)
              if (s0 + tt * 16 + rg + i > q0 + qs * 16 + r) st[qs][tt][i] = -3.0e38f;
      }

      // ---- in-lane max + 2 shuffles (exp2 domain) ----
      float vmax[2];
#pragma unroll
      for (int qs = 0; qs < 2; ++qs) {
        float v = st[qs][0][0];
#pragma unroll
        for (int tt = 0; tt < 4; ++tt)
#pragma unroll
          for (int i = 0; i < 4; ++i) v = fmaxf(v, st[qs][tt][i]);
        v = fmaxf(v, __shfl_xor(v, 16));
        v = fmaxf(v, __shfl_xor(v, 32));
        vmax[qs] = v;
      }
      // ---- defer-max rescale (thr 8 nats = 11.54 bits) ----
      const float grow = fmaxf(vmax[0] - m_[0], vmax[1] - m_[1]);
      if (!__all(grow <= 11.54f)) {
#pragma unroll
        for (int qs = 0; qs < 2; ++qs) {
          const float mn = fmaxf(m_[qs], vmax[qs]);
          const float cf = exp2f(m_[qs] - mn);
          l_[qs] *= cf;
          m_[qs] = mn;
#pragma unroll
          for (int tt = 0; tt < 8; ++tt)
#pragma unroll
            for (int i = 0; i < 4; ++i) o[qs][tt][i] *= cf;
        }
      }
      // ---- exp2 (in place) + sum + in-lane P fragments ----
      bf16x8 pa[2][2];
#pragma unroll
      for (int qs = 0; qs < 2; ++qs) {
        float ps = 0.f;
#pragma unroll
        for (int tt = 0; tt < 4; ++tt)
#pragma unroll
          for (int i = 0; i < 4; ++i) {
            st[qs][tt][i] = exp2f(st[qs][tt][i] - m_[qs]);
            ps += st[qs][tt][i];
          }
        ps += __shfl_xor(ps, 16);
        ps += __shfl_xor(ps, 32);
        l_[qs] += ps;
#pragma unroll
        for (int kb = 0; kb < 2; ++kb) {
          bf16x8 v;
#pragma unroll
          for (int j = 0; j < 8; ++j)
            v[j] = (short)f2b(st[qs][2 * kb + (j >> 2)][j & 3]);
          pa[qs][kb] = v;
        }
      }

      // ---- PV: O(32q x 128d) += P(32x64) @ V(64x128), keys interleaved in both ----
      __builtin_amdgcn_s_setprio(1);
#pragma unroll
      for (int tt = 0; tt < 8; ++tt) {
#pragma unroll
        for (int kb = 0; kb < 2; ++kb) {
          bf16x8 vf = *(const bf16x8*)(Vl + tt * 1024 + kb * 512 + lane * 8);
#pragma unroll
          for (int qs = 0; qs < 2; ++qs)
            o[qs][tt] = __builtin_amdgcn_mfma_f32_16x16x32_bf16(pa[qs][kb], vf, o[qs][tt], 0, 0, 0);
        }
      }
      __builtin_amdgcn_s_setprio(0);
    }

    __syncthreads();
    cur ^= 1;
  }

  // ---- epilogue: l_ lives at query=r lanes; o rows are query=rg+i -> shuffle ----
#pragma unroll
  for (int qs = 0; qs < 2; ++qs) {
    const float il = 1.f / l_[qs];
    float inv[4];
#pragma unroll
    for (int i = 0; i < 4; ++i)
      inv[i] = __shfl(il, (lane & 48) + rg + i);
    u16* op = attn_bf + (size_t)(b * LL + q0 + qs * 16 + rg) * DD + h * HDD;
#pragma unroll
    for (int tt = 0; tt < 8; ++tt)
#pragma unroll
      for (int i = 0; i < 4; ++i)
        op[(size_t)i * DD + tt * 16 + r] = f2b(o[qs][tt][i] * inv[i]);
  }
}

extern "C" void kernel_launch(void* const* d_in, const int* in_sizes, int n_in,
                              void* d_out, int out_size, void* d_ws, size_t ws_size,
                              hipStream_t stream) {
  const float* x    = (const float*)d_in[0];
  const float* cosb = (const float*)d_in[1];
  const float* sinb = (const float*)d_in[2];
  const float* Wq   = (const float*)d_in[3];
  const float* bq   = (const float*)d_in[4];
  const float* Wkv  = (const float*)d_in[5];
  const float* bkv  = (const float*)d_in[6];
  const float* Wrk  = (const float*)d_in[7];
  const float* brk  = (const float*)d_in[8];
  const float* Wo   = (const float*)d_in[9];
  const float* bo   = (const float*)d_in[10];
  float* out = (float*)d_out;

  char* ws = (char*)d_ws;
  float* kvbuf = (float*)(ws);
  float* krbuf = (float*)(ws + 8388608);
  float* qbuf  = (float*)(ws + 9437184);
  u16*   attn_bf = (u16*)(ws + 9437184);
  u16*   xb    = (u16*)(ws + 42991616);
  u16*   Qb    = (u16*)(ws + 42991616);
  u16*   Wob   = (u16*)(ws + 59768832);
  u16*   Wkvb  = (u16*)(ws + 68157440);
  u16*   Wrkb  = (u16*)(ws + 70254592);
  u16*   Wqb   = (u16*)(ws + 70516736);
  u16*   Kb    = (u16*)(ws + 70516736);
  u16*   VTb   = (u16*)(ws + 74711040);

  // 1) casts to bf16
  cast_bf16_kernel<<<(MM * DD / 4) / 256, 256, 0, stream>>>(x, xb, MM * DD / 4);
  cast_bf16_kernel<<<(HH * HDD * DD / 4) / 256, 256, 0, stream>>>(Wq, Wqb, HH * HDD * DD / 4);
  cast_bf16_kernel<<<(KVH * HDD * DD / 4) / 256, 256, 0, stream>>>(Wkv, Wkvb, KVH * HDD * DD / 4);
  cast_bf16_kernel<<<(RDD * DD / 4) / 256, 256, 0, stream>>>(Wrk, Wrkb, RDD * DD / 4);
  cast_bf16_kernel<<<(DD * HH * HDD / 4) / 256, 256, 0, stream>>>(Wo, Wob, DD * HH * HDD / 4);

  // 2) input projections (f32 out)
  gemm128<<<dim3(DD / 128, MM / 128), 256, 0, stream>>>(xb, Wqb, bq, qbuf, MM, DD, DD);
  gemm128<<<dim3((KVH * HDD) / 128, MM / 128), 256, 0, stream>>>(xb, Wkvb, bkv, kvbuf, MM, KVH * HDD, DD);
  gemm_bf16_nt<<<dim3(RDD / 16, MM / 16), 64, 0, stream>>>(xb, Wrkb, brk, krbuf, MM, RDD, DD);

  // 3) build bf16 attention operands in fragment/tile-image layouts
  build_k2<<<(BB * KVH * LL * HDD / 8) / 256, 256, 0, stream>>>(kvbuf, krbuf, cosb, sinb, Kb);
  build_v2<<<BB * KVH * 32, 256, 0, stream>>>(kvbuf, VTb);
  build_q2<<<(MM * HH * HDD / 8) / 256, 256, 0, stream>>>(qbuf, cosb, sinb, Qb);

  // 4) MFMA flash attention v8 -> bf16
  attn_mfma8<<<dim3(256), 512, 0, stream>>>(Qb, Kb, VTb, attn_bf);

  // 5) output projection -> d_out (f32)
  gemm128<<<dim3(DD / 128, MM / 128), 256, 0, stream>>>(attn_bf, Wob, bo, out, MM, DD, DD);
}